// Round 1
// baseline (812.807 us; speedup 1.0000x reference)
//
#include <hip/hip_runtime.h>

#define TT   512
#define HH   50
#define MB   8      // batch rows per block
#define NTIL 13     // 16-row gate tiles (52 units, 2 padded)

typedef _Float16 f16x8 __attribute__((ext_vector_type(8)));
typedef float    f32x4 __attribute__((ext_vector_type(4)));

__device__ __forceinline__ float sigm_f(float v) { return 1.0f / (1.0f + __expf(-v)); }
__device__ __forceinline__ float tanh_f(float v) {
    float a = fabsf(v);
    float e = __expf(-2.0f * a);
    float r = (1.0f - e) / (1.0f + e);
    return v < 0.0f ? -r : r;
}

// Block: 1024 threads = 16 waves. Wave w owns gate-tile w (units 4w..4w+3, rows
// interleaved i,f,g,o per unit). Each lane (q=l>>4, bcol=l&15) owns (unit u=4w+q,
// batch bcol): MFMA acc[e] = gate-type e of (u, bcol). c-state in registers.
__global__ __launch_bounds__(1024, 4)
void lstm2_kernel(const float* __restrict__ x,
                  const float* __restrict__ W_ih0, const float* __restrict__ W_hh0,
                  const float* __restrict__ b_ih0, const float* __restrict__ b_hh0,
                  const float* __restrict__ W_ih1, const float* __restrict__ W_hh1,
                  const float* __restrict__ b_ih1, const float* __restrict__ b_hh1,
                  const float* __restrict__ W_fc,  const float* __restrict__ b_fc,
                  float* __restrict__ out)
{
    // h staging, f16, double-buffered by parity. Row stride 72 f16 (144 B) so the
    // 16-B B-fragment reads land 2-way-conflict-max (free). Rows 8..15 and k 50..63
    // stay zero forever (batch/K padding).
    __shared__ __align__(16) _Float16 sh_h0[2][16][72];
    __shared__ __align__(16) _Float16 sh_h1[2][16][72];
    __shared__ float sh_x[MB][TT + 4];   // +4 pad: breaks stride-512 bank aliasing
    __shared__ float sh_h1f[MB][HH];
    __shared__ float sh_wfc[HH];

    const int tid  = threadIdx.x;
    const int w    = tid >> 6;
    const int l    = tid & 63;
    const int q    = l >> 4;
    const int bcol = l & 15;
    const int b0   = blockIdx.x * MB;

    for (int i = tid; i < 2 * 16 * 72; i += 1024) {
        (&sh_h0[0][0][0])[i] = (_Float16)0.0f;
        (&sh_h1[0][0][0])[i] = (_Float16)0.0f;
    }
    for (int i = tid; i < MB * TT; i += 1024) {
        int b = i >> 9, t = i & (TT - 1);
        sh_x[b][t] = x[(size_t)(b0 + b) * TT + t];
    }
    for (int i = tid; i < HH; i += 1024) sh_wfc[i] = W_fc[i];

    // ---- A fragments: weights, interleaved gate rows, resident in VGPRs ----
    // A row r (=lane&15) of tile w -> unit u_r = 4w + (r>>2), gate type r&3,
    // original weight row grow = (r&3)*50 + u_r.  k-map: k = ki*32 + q*8 + e
    // (same bijection used for the B fragments -> correct for any true HW k-map).
    const int r     = bcol;
    const int u_r   = w * 4 + (r >> 2);
    const int gt    = r & 3;
    const bool rowok = (w < NTIL) && (u_r < HH);
    const int grow  = gt * HH + (rowok ? u_r : 0);

    f16x8 wa_hh0[2], wa_ih1[2], wa_hh1[2];
    #pragma unroll
    for (int ki = 0; ki < 2; ++ki) {
        #pragma unroll
        for (int e = 0; e < 8; ++e) {
            int k = ki * 32 + q * 8 + e;
            bool ok = rowok && (k < HH);
            wa_hh0[ki][e] = ok ? (_Float16)W_hh0[grow * HH + k] : (_Float16)0.0f;
            wa_ih1[ki][e] = ok ? (_Float16)W_ih1[grow * HH + k] : (_Float16)0.0f;
            wa_hh1[ki][e] = ok ? (_Float16)W_hh1[grow * HH + k] : (_Float16)0.0f;
        }
    }

    // ---- per-lane elementwise constants for owned (u, bcol) ----
    const int u    = w * 4 + q;
    const bool uok = (w < NTIL) && (u < HH);
    float bi0[4], bi1[4], wi0[4];
    #pragma unroll
    for (int e = 0; e < 4; ++e) {
        int gr = e * HH + (uok ? u : 0);
        bi0[e] = uok ? (b_ih0[gr] + b_hh0[gr]) : 0.0f;
        bi1[e] = uok ? (b_ih1[gr] + b_hh1[gr]) : 0.0f;
        wi0[e] = uok ? W_ih0[gr] : 0.0f;
    }
    const bool wrok = uok && (bcol < MB);

    float c0 = 0.0f, c1 = 0.0f, h1last = 0.0f;

    __syncthreads();

    for (int t = 0; t < TT; ++t) {
        const int cur = t & 1, nxt = cur ^ 1;
        const float xi = sh_x[bcol & 7][t];
        f16x8 pb0 = {(_Float16)0, (_Float16)0, (_Float16)0, (_Float16)0,
                     (_Float16)0, (_Float16)0, (_Float16)0, (_Float16)0};
        f16x8 pb1 = pb0;

        if (w < NTIL) {
            // B frags: h0(t-1); also prefetch h1(t-1) frags for layer 1
            f16x8 hb0 = *(const f16x8*)&sh_h0[cur][bcol][q * 8];
            f16x8 hb1 = *(const f16x8*)&sh_h0[cur][bcol][32 + q * 8];
            pb0 = *(const f16x8*)&sh_h1[cur][bcol][q * 8];
            pb1 = *(const f16x8*)&sh_h1[cur][bcol][32 + q * 8];

            f32x4 acc = {0.0f, 0.0f, 0.0f, 0.0f};
            acc = __builtin_amdgcn_mfma_f32_16x16x32_f16(wa_hh0[0], hb0, acc, 0, 0, 0);
            acc = __builtin_amdgcn_mfma_f32_16x16x32_f16(wa_hh0[1], hb1, acc, 0, 0, 0);

            float gi = acc[0] + bi0[0] + xi * wi0[0];
            float gf = acc[1] + bi0[1] + xi * wi0[1];
            float gg = acc[2] + bi0[2] + xi * wi0[2];
            float go = acc[3] + bi0[3] + xi * wi0[3];
            float I = sigm_f(gi), F = sigm_f(gf), G = tanh_f(gg), O = sigm_f(go);
            c0 = F * c0 + I * G;
            float h0v = O * tanh_f(c0);
            if (wrok) sh_h0[nxt][bcol][u] = (_Float16)h0v;
        }
        __syncthreads();   // h0(t) visible
        if (w < NTIL) {
            f16x8 nb0 = *(const f16x8*)&sh_h0[nxt][bcol][q * 8];
            f16x8 nb1 = *(const f16x8*)&sh_h0[nxt][bcol][32 + q * 8];

            f32x4 acc = {0.0f, 0.0f, 0.0f, 0.0f};
            acc = __builtin_amdgcn_mfma_f32_16x16x32_f16(wa_ih1[0], nb0, acc, 0, 0, 0);
            acc = __builtin_amdgcn_mfma_f32_16x16x32_f16(wa_ih1[1], nb1, acc, 0, 0, 0);
            acc = __builtin_amdgcn_mfma_f32_16x16x32_f16(wa_hh1[0], pb0, acc, 0, 0, 0);
            acc = __builtin_amdgcn_mfma_f32_16x16x32_f16(wa_hh1[1], pb1, acc, 0, 0, 0);

            float gi = acc[0] + bi1[0];
            float gf = acc[1] + bi1[1];
            float gg = acc[2] + bi1[2];
            float go = acc[3] + bi1[3];
            float I = sigm_f(gi), F = sigm_f(gf), G = tanh_f(gg), O = sigm_f(go);
            c1 = F * c1 + I * G;
            float h1v = O * tanh_f(c1);
            h1last = h1v;
            if (wrok) sh_h1[nxt][bcol][u] = (_Float16)h1v;
        }
        __syncthreads();   // h1(t) visible for next step
    }

    if (wrok) sh_h1f[bcol][u] = h1last;
    __syncthreads();

    if (tid < MB) {
        float s = b_fc[0];
        for (int j = 0; j < HH; ++j) s += sh_h1f[tid][j] * sh_wfc[j];
        out[b0 + tid] = s;
    }
}

extern "C" void kernel_launch(void* const* d_in, const int* in_sizes, int n_in,
                              void* d_out, int out_size, void* d_ws, size_t ws_size,
                              hipStream_t stream) {
    const float* xin   = (const float*)d_in[0];
    const float* W_ih0 = (const float*)d_in[1];
    const float* W_hh0 = (const float*)d_in[2];
    const float* b_ih0 = (const float*)d_in[3];
    const float* b_hh0 = (const float*)d_in[4];
    const float* W_ih1 = (const float*)d_in[5];
    const float* W_hh1 = (const float*)d_in[6];
    const float* b_ih1 = (const float*)d_in[7];
    const float* b_hh1 = (const float*)d_in[8];
    const float* W_fc  = (const float*)d_in[9];
    const float* b_fc  = (const float*)d_in[10];
    float* out = (float*)d_out;

    lstm2_kernel<<<dim3(2048 / MB), dim3(1024), 0, stream>>>(
        xin, W_ih0, W_hh0, b_ih0, b_hh0, W_ih1, W_hh1, b_ih1, b_hh1, W_fc, b_fc, out);
}

// Round 2
// 473.423 us; speedup vs baseline: 1.7169x; 1.7169x over previous
//
#include <hip/hip_runtime.h>

#define TT   512
#define HH   50
#define MB   8      // batch rows per block
#define NTIL 13     // 16-row gate tiles (52 units, 2 padded)

typedef _Float16 f16x8 __attribute__((ext_vector_type(8)));
typedef float    f32x4 __attribute__((ext_vector_type(4)));

#define LOG2E  1.4426950408889634f

__device__ __forceinline__ float fast_rcp(float v)  { return __builtin_amdgcn_rcpf(v); }
__device__ __forceinline__ float fast_exp2(float v) { return __builtin_amdgcn_exp2f(v); }

// sigmoid: 1/(1+2^(-x*log2e)).  x->-inf: exp2->inf, rcp(inf)=0 OK. x->+inf: rcp(1)=1 OK.
__device__ __forceinline__ float sigm_f(float v) {
    return fast_rcp(1.0f + fast_exp2(v * -LOG2E));
}
// tanh: (t-1)/(t+1), t=2^(2x*log2e). Clamp to +-15 (tanh(15)==1.0f in f32) to avoid inf/inf.
__device__ __forceinline__ float tanh_f(float v) {
    float vc = fminf(fmaxf(v, -15.0f), 15.0f);
    float t  = fast_exp2(vc * (2.0f * LOG2E));
    return (t - 1.0f) * fast_rcp(t + 1.0f);
}

// Block: 1024 threads = 16 waves; waves 0..12 own gate-tile w (units 4w..4w+3,
// rows interleaved i,f,g,o per unit). Lane (q=l>>4, bcol=l&15) owns (u=4w+q, bcol);
// MFMA acc[e] = gate e of (u,bcol). c-state in registers.
// Layer 1 runs pipelined one step behind layer 0 -> ONE barrier per timestep.
__global__ __launch_bounds__(1024, 4)
void lstm2_kernel(const float* __restrict__ x,
                  const float* __restrict__ W_ih0, const float* __restrict__ W_hh0,
                  const float* __restrict__ b_ih0, const float* __restrict__ b_hh0,
                  const float* __restrict__ W_ih1, const float* __restrict__ W_hh1,
                  const float* __restrict__ b_ih1, const float* __restrict__ b_hh1,
                  const float* __restrict__ W_fc,  const float* __restrict__ b_fc,
                  float* __restrict__ out)
{
    // h staging, f16, double-buffered by parity. Row stride 72 f16 (144 B): the
    // 16B B-fragment reads of 8 consecutive lanes cover all 32 banks (conflict-free).
    __shared__ __align__(16) _Float16 sh_h0[2][16][72];
    __shared__ __align__(16) _Float16 sh_h1[2][16][72];
    __shared__ float sh_x[MB][TT + 4];
    __shared__ float sh_h1f[MB][HH];
    __shared__ float sh_wfc[HH];

    const int tid  = threadIdx.x;
    const int w    = tid >> 6;
    const int l    = tid & 63;
    const int q    = l >> 4;
    const int bcol = l & 15;
    const int b0   = blockIdx.x * MB;

    for (int i = tid; i < 2 * 16 * 72; i += 1024) {
        (&sh_h0[0][0][0])[i] = (_Float16)0.0f;
        (&sh_h1[0][0][0])[i] = (_Float16)0.0f;
    }
    for (int i = tid; i < MB * TT; i += 1024) {
        int b = i >> 9, t = i & (TT - 1);
        sh_x[b][t] = x[(size_t)(b0 + b) * TT + t];
    }
    for (int i = tid; i < HH; i += 1024) sh_wfc[i] = W_fc[i];

    // ---- A fragments (weights) resident in VGPRs. Row r=lane&15 of tile w ->
    // unit u_r = 4w + (r>>2), gate type r&3, weight row grow = (r&3)*50 + u_r.
    // k-map: k = ki*32 + q*8 + e (same bijection as B fragments -> sum correct).
    const int r      = bcol;
    const int u_r    = w * 4 + (r >> 2);
    const int gt     = r & 3;
    const bool rowok = (w < NTIL) && (u_r < HH);
    const int grow   = gt * HH + (rowok ? u_r : 0);

    f16x8 wa_hh0[2], wa_ih1[2], wa_hh1[2];
    #pragma unroll
    for (int ki = 0; ki < 2; ++ki) {
        #pragma unroll
        for (int e = 0; e < 8; ++e) {
            int k = ki * 32 + q * 8 + e;
            bool ok = rowok && (k < HH);
            wa_hh0[ki][e] = ok ? (_Float16)W_hh0[grow * HH + k] : (_Float16)0.0f;
            wa_ih1[ki][e] = ok ? (_Float16)W_ih1[grow * HH + k] : (_Float16)0.0f;
            wa_hh1[ki][e] = ok ? (_Float16)W_hh1[grow * HH + k] : (_Float16)0.0f;
        }
    }

    // ---- per-lane elementwise constants for owned (u, bcol) ----
    const int u    = w * 4 + q;
    const bool uok = (w < NTIL) && (u < HH);
    float bi0[4], bi1[4], wi0[4];
    #pragma unroll
    for (int e = 0; e < 4; ++e) {
        int gr = e * HH + (uok ? u : 0);
        bi0[e] = uok ? (b_ih0[gr] + b_hh0[gr]) : 0.0f;
        bi1[e] = uok ? (b_ih1[gr] + b_hh1[gr]) : 0.0f;
        wi0[e] = uok ? W_ih0[gr] : 0.0f;
    }
    const bool wrok = uok && (bcol < MB);

    float c0 = 0.0f, c1 = 0.0f;

    __syncthreads();

    // Phase t computes h0(t) and h1(t-1).  c = t&1:
    //   read  h0(t-1) <- sh_h0[c^1],  h1(t-2) <- sh_h1[c]
    //   write h0(t)   -> sh_h0[c],    h1(t-1) -> sh_h1[c^1]
    for (int t = 0; t < TT; ++t) {
        const int c = t & 1;
        if (w < NTIL) {
            const float xi = sh_x[bcol & 7][t];
            f16x8 hb0 = *(const f16x8*)&sh_h0[c ^ 1][bcol][0];
            f16x8 hb1 = *(const f16x8*)&sh_h0[c ^ 1][bcol][32];
            // re-slice: fragment e-range is q*8; the [0]/[32] loads above are wrong
            // per-lane — load per-lane offsets:
            hb0 = *(const f16x8*)&sh_h0[c ^ 1][bcol][q * 8];
            hb1 = *(const f16x8*)&sh_h0[c ^ 1][bcol][32 + q * 8];

            // ---- layer 0: h0(t) ----
            f32x4 acc0 = {0.0f, 0.0f, 0.0f, 0.0f};
            acc0 = __builtin_amdgcn_mfma_f32_16x16x32_f16(wa_hh0[0], hb0, acc0, 0, 0, 0);
            acc0 = __builtin_amdgcn_mfma_f32_16x16x32_f16(wa_hh0[1], hb1, acc0, 0, 0, 0);

            float gi0 = acc0[0] + bi0[0] + xi * wi0[0];
            float gf0 = acc0[1] + bi0[1] + xi * wi0[1];
            float gg0 = acc0[2] + bi0[2] + xi * wi0[2];
            float go0 = acc0[3] + bi0[3] + xi * wi0[3];
            float I0 = sigm_f(gi0), F0 = sigm_f(gf0), G0 = tanh_f(gg0), O0 = sigm_f(go0);
            c0 = F0 * c0 + I0 * G0;
            float h0v = O0 * tanh_f(c0);
            if (wrok) sh_h0[c][bcol][u] = (_Float16)h0v;

            // ---- layer 1: h1(t-1), uses same h0(t-1) fragments ----
            if (t > 0) {
                f16x8 pb0 = *(const f16x8*)&sh_h1[c][bcol][q * 8];
                f16x8 pb1 = *(const f16x8*)&sh_h1[c][bcol][32 + q * 8];

                f32x4 acc1 = {0.0f, 0.0f, 0.0f, 0.0f};
                acc1 = __builtin_amdgcn_mfma_f32_16x16x32_f16(wa_ih1[0], hb0, acc1, 0, 0, 0);
                acc1 = __builtin_amdgcn_mfma_f32_16x16x32_f16(wa_ih1[1], hb1, acc1, 0, 0, 0);
                acc1 = __builtin_amdgcn_mfma_f32_16x16x32_f16(wa_hh1[0], pb0, acc1, 0, 0, 0);
                acc1 = __builtin_amdgcn_mfma_f32_16x16x32_f16(wa_hh1[1], pb1, acc1, 0, 0, 0);

                float gi1 = acc1[0] + bi1[0];
                float gf1 = acc1[1] + bi1[1];
                float gg1 = acc1[2] + bi1[2];
                float go1 = acc1[3] + bi1[3];
                float I1 = sigm_f(gi1), F1 = sigm_f(gf1), G1 = tanh_f(gg1), O1 = sigm_f(go1);
                c1 = F1 * c1 + I1 * G1;
                float h1v = O1 * tanh_f(c1);
                if (wrok) sh_h1[c ^ 1][bcol][u] = (_Float16)h1v;
            }
        }
        __syncthreads();
    }

    // ---- tail: h1(TT-1) from h0(TT-1) (sh_h0 buf[(TT-1)&1=1]) and h1(TT-2) (sh_h1 buf[0]) ----
    float h1last = 0.0f;
    if (w < NTIL) {
        f16x8 hb0 = *(const f16x8*)&sh_h0[1][bcol][q * 8];
        f16x8 hb1 = *(const f16x8*)&sh_h0[1][bcol][32 + q * 8];
        f16x8 pb0 = *(const f16x8*)&sh_h1[0][bcol][q * 8];
        f16x8 pb1 = *(const f16x8*)&sh_h1[0][bcol][32 + q * 8];

        f32x4 acc1 = {0.0f, 0.0f, 0.0f, 0.0f};
        acc1 = __builtin_amdgcn_mfma_f32_16x16x32_f16(wa_ih1[0], hb0, acc1, 0, 0, 0);
        acc1 = __builtin_amdgcn_mfma_f32_16x16x32_f16(wa_ih1[1], hb1, acc1, 0, 0, 0);
        acc1 = __builtin_amdgcn_mfma_f32_16x16x32_f16(wa_hh1[0], pb0, acc1, 0, 0, 0);
        acc1 = __builtin_amdgcn_mfma_f32_16x16x32_f16(wa_hh1[1], pb1, acc1, 0, 0, 0);

        float gi1 = acc1[0] + bi1[0];
        float gf1 = acc1[1] + bi1[1];
        float gg1 = acc1[2] + bi1[2];
        float go1 = acc1[3] + bi1[3];
        float I1 = sigm_f(gi1), F1 = sigm_f(gf1), G1 = tanh_f(gg1), O1 = sigm_f(go1);
        c1 = F1 * c1 + I1 * G1;
        h1last = O1 * tanh_f(c1);
    }

    if (wrok) sh_h1f[bcol][u] = h1last;
    __syncthreads();

    if (tid < MB) {
        float s = b_fc[0];
        for (int j = 0; j < HH; ++j) s += sh_h1f[tid][j] * sh_wfc[j];
        out[b0 + tid] = s;
    }
}

extern "C" void kernel_launch(void* const* d_in, const int* in_sizes, int n_in,
                              void* d_out, int out_size, void* d_ws, size_t ws_size,
                              hipStream_t stream) {
    const float* xin   = (const float*)d_in[0];
    const float* W_ih0 = (const float*)d_in[1];
    const float* W_hh0 = (const float*)d_in[2];
    const float* b_ih0 = (const float*)d_in[3];
    const float* b_hh0 = (const float*)d_in[4];
    const float* W_ih1 = (const float*)d_in[5];
    const float* W_hh1 = (const float*)d_in[6];
    const float* b_ih1 = (const float*)d_in[7];
    const float* b_hh1 = (const float*)d_in[8];
    const float* W_fc  = (const float*)d_in[9];
    const float* b_fc  = (const float*)d_in[10];
    float* out = (float*)d_out;

    lstm2_kernel<<<dim3(2048 / MB), dim3(1024), 0, stream>>>(
        xin, W_ih0, W_hh0, b_ih0, b_hh0, W_ih1, W_hh1, b_ih1, b_hh1, W_fc, b_fc, out);
}

// Round 3
// 408.882 us; speedup vs baseline: 1.9879x; 1.1578x over previous
//
#include <hip/hip_runtime.h>

#define TT   512
#define HH   50
#define MB   8            // real batch rows per block
#define NW   13           // waves per block
#define NTHR (NW * 64)    // 832 threads
#define UPAD 52           // padded unit count (13 tiles x 4)
#define NQ   (UPAD * MB)  // 416 quads per layer

typedef _Float16 f16x8 __attribute__((ext_vector_type(8)));
typedef float    f32x4 __attribute__((ext_vector_type(4)));

#define LOG2E 1.4426950408889634f

__device__ __forceinline__ float fast_rcp(float v)  { return __builtin_amdgcn_rcpf(v); }
__device__ __forceinline__ float fast_exp2(float v) { return __builtin_amdgcn_exp2f(v); }
// sigma(x) = 1/(1+2^(-x*log2e)); saturates correctly via exp2->inf, rcp(inf)=0.
__device__ __forceinline__ float sigm_f(float v) { return fast_rcp(1.0f + fast_exp2(v * -LOG2E)); }
// tanh(x) = 2*sigma(2x) - 1; no clamp needed (inf-safe).
__device__ __forceinline__ float tanh_f(float v) { return __builtin_fmaf(2.0f, sigm_f(2.0f * v), -1.0f); }

// Block: 832 threads = 13 waves, grid = 256 (one batch-group of 8 per block).
// Phase A: wave w computes gate-tile w (units 4w..4w+3, rows interleaved i,f,g,o)
//   for both layers via MFMA; lanes bcol<8 write f32 quads to sh_g.
// Phase C: flat lane j handles one (layer, unit, batch) quad: reads sh_g linearly,
//   runs gates->c->h in-register (c-state lives in this lane), writes h (f16) to sh_h.
// Layer 1 is pipelined one step behind layer 0 -> step t computes h0(t), h1(t-1).
__global__ __launch_bounds__(NTHR, 1)
void lstm2_kernel(const float* __restrict__ x,
                  const float* __restrict__ W_ih0, const float* __restrict__ W_hh0,
                  const float* __restrict__ b_ih0, const float* __restrict__ b_hh0,
                  const float* __restrict__ W_ih1, const float* __restrict__ W_hh1,
                  const float* __restrict__ b_ih1, const float* __restrict__ b_hh1,
                  const float* __restrict__ W_fc,  const float* __restrict__ b_fc,
                  float* __restrict__ out)
{
    // sh_h[l][p][b][k]: h for layer l, parity buffer p. Row stride 72 f16 = 144 B.
    __shared__ __align__(16) _Float16 sh_h[2][2][16][72];   // 9216 B
    __shared__ __align__(16) float    sh_g[2][UPAD][MB][4]; // 13312 B, gate quads
    __shared__ float sh_x[MB][TT + 4];                      // 16512 B
    __shared__ float sh_wfc[HH];

    const int tid  = threadIdx.x;
    const int w    = tid >> 6;
    const int l    = tid & 63;
    const int q    = l >> 4;
    const int bcol = l & 15;
    const int b0   = blockIdx.x * MB;

    for (int i = tid; i < 2 * 2 * 16 * 72; i += NTHR) (&sh_h[0][0][0][0])[i] = (_Float16)0.0f;
    for (int i = tid; i < MB * TT; i += NTHR) {
        int b = i >> 9, t = i & (TT - 1);
        sh_x[b][t] = x[(size_t)b0 * TT + i];   // contiguous & coalesced
    }
    for (int i = tid; i < HH; i += NTHR) sh_wfc[i] = W_fc[i];

    // ---- Phase-A A-fragments (weights) in VGPRs. A-row r=lane&15 of tile w ->
    // unit u_r = 4w+(r>>2), gate r&3, weight row grow = (r&3)*HH + u_r.
    // k-map: k = ki*32 + q*8 + e (same bijection as B frags -> sum correct).
    {
    }
    const int r      = bcol;
    const int u_r    = w * 4 + (r >> 2);
    const bool rowok = (u_r < HH);
    const int grow   = (r & 3) * HH + (rowok ? u_r : 0);

    f16x8 wa_hh0[2], wa_ih1[2], wa_hh1[2];
    #pragma unroll
    for (int ki = 0; ki < 2; ++ki) {
        #pragma unroll
        for (int e = 0; e < 8; ++e) {
            int k = ki * 32 + q * 8 + e;
            bool ok = rowok && (k < HH);
            wa_hh0[ki][e] = ok ? (_Float16)W_hh0[grow * HH + k] : (_Float16)0.0f;
            wa_ih1[ki][e] = ok ? (_Float16)W_ih1[grow * HH + k] : (_Float16)0.0f;
            wa_hh1[ki][e] = ok ? (_Float16)W_hh1[grow * HH + k] : (_Float16)0.0f;
        }
    }

    // ---- Phase-C lane identity: j -> (layer, unit cu, batch cb) ----
    const int  j   = tid;
    const bool lay = (j >= NQ);
    const int  jj  = lay ? (j - NQ) : j;
    const int  cu  = jj >> 3;       // 0..51
    const int  cb  = jj & 7;
    const bool cuok = (cu < HH);
    const int  cuc  = cuok ? cu : 0;

    float bza[4], wza[4];
    #pragma unroll
    for (int e = 0; e < 4; ++e) {
        int gr = e * HH + cuc;
        float bb = lay ? (b_ih1[gr] + b_hh1[gr]) : (b_ih0[gr] + b_hh0[gr]);
        bza[e] = cuok ? bb : 0.0f;
        wza[e] = (!lay && cuok) ? W_ih0[gr] : 0.0f;
    }

    // ---- precomputed LDS pointers (loop-invariant; parity via literals) ----
    const _Float16* rA0 = &sh_h[0][1][bcol][q * 8];  // P=0: h0(t-1) in buf 1
    const _Float16* rB0 = &sh_h[1][0][bcol][q * 8];  // P=0: h1(t-2) in buf 0
    const _Float16* rA1 = &sh_h[0][0][bcol][q * 8];  // P=1
    const _Float16* rB1 = &sh_h[1][1][bcol][q * 8];  // P=1
    f32x4* gw0 = (f32x4*)&sh_g[0][4 * w + q][bcol < MB ? bcol : 0][0];
    f32x4* gw1 = (f32x4*)&sh_g[1][4 * w + q][bcol < MB ? bcol : 0][0];
    const f32x4* gqp = (const f32x4*)&sh_g[lay ? 1 : 0][cu][cb][0];
    // h write targets: layer0 -> sh_h[0][P], layer1 -> sh_h[1][P^1]
    _Float16* hw0 = &sh_h[lay ? 1 : 0][lay ? 1 : 0][cb][cuc];  // even body (P=0)
    _Float16* hw1 = &sh_h[lay ? 1 : 0][lay ? 0 : 1][cb][cuc];  // odd  body (P=1)
    const float* xq = &sh_x[cb][0];

    const bool wr = cuok;
    float cst = 0.0f;

    __syncthreads();

#define STEP_BODY(P, T0, XI)                                                      \
    {                                                                             \
        f16x8 hb0_ = *(const f16x8*)(P ? rA1 : rA0);                              \
        f16x8 hb1_ = *(const f16x8*)((P ? rA1 : rA0) + 32);                       \
        f16x8 pb0_ = *(const f16x8*)(P ? rB1 : rB0);                              \
        f16x8 pb1_ = *(const f16x8*)((P ? rB1 : rB0) + 32);                       \
        f32x4 a0_ = {0.0f, 0.0f, 0.0f, 0.0f};                                     \
        f32x4 a1_ = {0.0f, 0.0f, 0.0f, 0.0f};                                     \
        a0_ = __builtin_amdgcn_mfma_f32_16x16x32_f16(wa_hh0[0], hb0_, a0_, 0,0,0);\
        a0_ = __builtin_amdgcn_mfma_f32_16x16x32_f16(wa_hh0[1], hb1_, a0_, 0,0,0);\
        a1_ = __builtin_amdgcn_mfma_f32_16x16x32_f16(wa_ih1[0], hb0_, a1_, 0,0,0);\
        a1_ = __builtin_amdgcn_mfma_f32_16x16x32_f16(wa_ih1[1], hb1_, a1_, 0,0,0);\
        a1_ = __builtin_amdgcn_mfma_f32_16x16x32_f16(wa_hh1[0], pb0_, a1_, 0,0,0);\
        a1_ = __builtin_amdgcn_mfma_f32_16x16x32_f16(wa_hh1[1], pb1_, a1_, 0,0,0);\
        if (bcol < MB) { *gw0 = a0_; *gw1 = a1_; }                                \
        __syncthreads();                                                          \
        f32x4 gq_ = *gqp;                                                         \
        float xi_ = (XI);                                                         \
        float gi_ = gq_[0] + bza[0] + xi_ * wza[0];                               \
        float gf_ = gq_[1] + bza[1] + xi_ * wza[1];                               \
        float gg_ = gq_[2] + bza[2] + xi_ * wza[2];                               \
        float go_ = gq_[3] + bza[3] + xi_ * wza[3];                               \
        float I_ = sigm_f(gi_), F_ = sigm_f(gf_);                                 \
        float G_ = tanh_f(gg_), O_ = sigm_f(go_);                                 \
        float cn_ = __builtin_fmaf(F_, cst, I_ * G_);                             \
        if (T0) cn_ = lay ? 0.0f : cn_;                                           \
        cst = cn_;                                                                \
        float hv_ = O_ * tanh_f(cst);                                             \
        if (wr && (!(T0) || !lay)) *(P ? hw1 : hw0) = (_Float16)hv_;              \
        __syncthreads();                                                          \
    }

    // t = 0 (even parity), layer-1 c-update & write suppressed (h1(-1) must stay 0)
    STEP_BODY(0, true, xq[0])

    // t = 1..512: 256 unrolled (odd, even) pairs; t=512 writes h1(511) -> sh_h[1][1]
    for (int k2 = 0; k2 < 256; ++k2) {
        STEP_BODY(1, false, xq[1])
        STEP_BODY(0, false, xq[2])
        xq += 2;
    }
#undef STEP_BODY

    // ---- FC epilogue: out[b] = sum_u h1(511)[b][u] * wfc[u] + b_fc ----
    if (tid < MB) {
        float s = b_fc[0];
        for (int u = 0; u < HH; ++u)
            s += (float)sh_h[1][1][tid][u] * sh_wfc[u];
        out[b0 + tid] = s;
    }
}

extern "C" void kernel_launch(void* const* d_in, const int* in_sizes, int n_in,
                              void* d_out, int out_size, void* d_ws, size_t ws_size,
                              hipStream_t stream) {
    const float* xin   = (const float*)d_in[0];
    const float* W_ih0 = (const float*)d_in[1];
    const float* W_hh0 = (const float*)d_in[2];
    const float* b_ih0 = (const float*)d_in[3];
    const float* b_hh0 = (const float*)d_in[4];
    const float* W_ih1 = (const float*)d_in[5];
    const float* W_hh1 = (const float*)d_in[6];
    const float* b_ih1 = (const float*)d_in[7];
    const float* b_hh1 = (const float*)d_in[8];
    const float* W_fc  = (const float*)d_in[9];
    const float* b_fc  = (const float*)d_in[10];
    float* out = (float*)d_out;

    lstm2_kernel<<<dim3(2048 / MB), dim3(NTHR), 0, stream>>>(
        xin, W_ih0, W_hh0, b_ih0, b_hh0, W_ih1, W_hh1, b_ih1, b_hh1, W_fc, b_fc, out);
}

// Round 4
// 318.938 us; speedup vs baseline: 2.5485x; 1.2820x over previous
//
#include <hip/hip_runtime.h>

#define TT   512
#define HH   50
#define MB   8            // batch rows per block
#define NW   13           // waves per block
#define NTHR (NW * 64)    // 832 threads

typedef _Float16 f16x8 __attribute__((ext_vector_type(8)));
typedef float    f32x4 __attribute__((ext_vector_type(4)));

#define LOG2E 1.4426950408889634f

__device__ __forceinline__ float fast_rcp(float v)  { return __builtin_amdgcn_rcpf(v); }
__device__ __forceinline__ float fast_exp2(float v) { return __builtin_amdgcn_exp2f(v); }
// sigma(x) = 1/(1+2^(-x*log2e)); inf-safe at both ends.
__device__ __forceinline__ float sigm_f(float v) { return fast_rcp(1.0f + fast_exp2(v * -LOG2E)); }
// tanh(x) = 2*sigma(2x) - 1; inf-safe.
__device__ __forceinline__ float tanh_f(float v) { return __builtin_fmaf(2.0f, sigm_f(2.0f * v), -1.0f); }

// 13 waves. Wave w owns gate-tile w (units 4w..4w+3, A-rows interleaved i,f,g,o).
// Lane (q=l>>4, n=l&15): MFMA acc[e] = gate e of unit u=4w+q, batch col n.
// After MFMAs, layer-1 quads are shfl_xor'd from lanes n<8 to lanes n>=8:
// lanes n<8 run the L0 gate chain for (u, n); lanes n>=8 run L1 for (u, n-8).
// ONE barrier per step. L1 pipelined one step behind L0.
__global__ __launch_bounds__(NTHR, 1)
void lstm2_kernel(const float* __restrict__ x,
                  const float* __restrict__ W_ih0, const float* __restrict__ W_hh0,
                  const float* __restrict__ b_ih0, const float* __restrict__ b_hh0,
                  const float* __restrict__ W_ih1, const float* __restrict__ W_hh1,
                  const float* __restrict__ b_ih1, const float* __restrict__ b_hh1,
                  const float* __restrict__ W_fc,  const float* __restrict__ b_fc,
                  float* __restrict__ out)
{
    // h storage: [layer][parity buf][ki][q][col][e] — lane (q,n) reads the 16B
    // f16x8 at [L][p][ki][q][n]; unit u lives at (ki=u>>5, q=(u>>3)&3, e=u&7).
    __shared__ __align__(16) _Float16 shh[2][2][2][4][16][8];   // 8 KiB
    __shared__ float sh_x[MB][TT + 4];
    __shared__ float shf[MB][HH];
    __shared__ float sh_wfc[HH];

    const int tid = threadIdx.x;
    const int w   = tid >> 6;
    const int l   = tid & 63;
    const int q   = l >> 4;
    const int n   = l & 15;
    const int b0  = blockIdx.x * MB;

    for (int i = tid; i < 2 * 2 * 2 * 4 * 16 * 8; i += NTHR)
        (&shh[0][0][0][0][0][0])[i] = (_Float16)0.0f;
    for (int i = tid; i < MB * TT; i += NTHR) {
        int b = i >> 9, t = i & (TT - 1);
        sh_x[b][t] = x[(size_t)b0 * TT + i];
    }
    for (int i = tid; i < HH; i += NTHR) sh_wfc[i] = W_fc[i];

    // ---- A fragments (weights) in VGPRs. A-row r = n -> unit 4w+(r>>2), gate r&3,
    // weight row grow = (r&3)*HH + u_r. k-map: k = ki*32 + q*8 + e (same bijection
    // used for B-layout above -> sums correct regardless of true HW k-map).
    const int  r     = n;
    const int  u_r   = w * 4 + (r >> 2);
    const bool rowok = (u_r < HH);
    const int  grow  = (r & 3) * HH + (rowok ? u_r : 0);

    f16x8 wa_hh0[2], wa_ih1[2], wa_hh1[2];
    #pragma unroll
    for (int ki = 0; ki < 2; ++ki) {
        #pragma unroll
        for (int e = 0; e < 8; ++e) {
            int k = ki * 32 + q * 8 + e;
            bool ok = rowok && (k < HH);
            wa_hh0[ki][e] = ok ? (_Float16)W_hh0[grow * HH + k] : (_Float16)0.0f;
            wa_ih1[ki][e] = ok ? (_Float16)W_ih1[grow * HH + k] : (_Float16)0.0f;
            wa_hh1[ki][e] = ok ? (_Float16)W_hh1[grow * HH + k] : (_Float16)0.0f;
        }
    }

    // ---- elementwise lane identity ----
    const bool isL1 = (n >= 8);
    const int  u    = w * 4 + q;
    const bool wr   = (u < HH);
    const int  uc   = wr ? u : 0;
    const int  cb   = n & 7;

    float bza[4], wza[4];
    #pragma unroll
    for (int e = 0; e < 4; ++e) {
        int gr = e * HH + uc;
        bza[e] = isL1 ? (b_ih1[gr] + b_hh1[gr]) : (b_ih0[gr] + b_hh0[gr]);
        wza[e] = isL1 ? 0.0f : W_ih0[gr];
    }

    // write ptrs: lane's h value (layer isL1, unit uc, col cb) -> buf p^1
    _Float16* wpt0 = &shh[isL1 ? 1 : 0][1][uc >> 5][(uc >> 3) & 3][cb][uc & 7]; // P=0 step
    _Float16* wpt1 = &shh[isL1 ? 1 : 0][0][uc >> 5][(uc >> 3) & 3][cb][uc & 7]; // P=1 step

    const float* xq = &sh_x[cb][0];
    float cst = 0.0f;

    __syncthreads();

#define RD(L, P, KI) (*(const f16x8*)&shh[L][P][KI][q][n][0])

#define STEP(P, T0, XI)                                                            \
    {                                                                              \
        f16x8 hb0_ = RD(0, P, 0), hb1_ = RD(0, P, 1);                              \
        f16x8 pb0_ = RD(1, P, 0), pb1_ = RD(1, P, 1);                              \
        f32x4 z_ = {0.0f, 0.0f, 0.0f, 0.0f};                                       \
        f32x4 a0_ = __builtin_amdgcn_mfma_f32_16x16x32_f16(wa_hh0[0], hb0_, z_, 0,0,0); \
        a0_ = __builtin_amdgcn_mfma_f32_16x16x32_f16(wa_hh0[1], hb1_, a0_, 0,0,0); \
        f32x4 a1_ = __builtin_amdgcn_mfma_f32_16x16x32_f16(wa_ih1[0], hb0_, z_, 0,0,0); \
        a1_ = __builtin_amdgcn_mfma_f32_16x16x32_f16(wa_ih1[1], hb1_, a1_, 0,0,0); \
        f32x4 a2_ = __builtin_amdgcn_mfma_f32_16x16x32_f16(wa_hh1[0], pb0_, z_, 0,0,0); \
        a2_ = __builtin_amdgcn_mfma_f32_16x16x32_f16(wa_hh1[1], pb1_, a2_, 0,0,0); \
        a1_ += a2_;                                                                \
        float s0_ = __shfl_xor(a1_[0], 8), s1_ = __shfl_xor(a1_[1], 8);            \
        float s2_ = __shfl_xor(a1_[2], 8), s3_ = __shfl_xor(a1_[3], 8);            \
        float xi_ = (XI);                                                          \
        float g0_ = __builtin_fmaf(xi_, wza[0], (isL1 ? s0_ : a0_[0]) + bza[0]);   \
        float g1_ = __builtin_fmaf(xi_, wza[1], (isL1 ? s1_ : a0_[1]) + bza[1]);   \
        float g2_ = __builtin_fmaf(xi_, wza[2], (isL1 ? s2_ : a0_[2]) + bza[2]);   \
        float g3_ = __builtin_fmaf(xi_, wza[3], (isL1 ? s3_ : a0_[3]) + bza[3]);   \
        float I_ = sigm_f(g0_), F_ = sigm_f(g1_);                                  \
        float G_ = tanh_f(g2_), O_ = sigm_f(g3_);                                  \
        float cn_ = __builtin_fmaf(F_, cst, I_ * G_);                              \
        cst = ((T0) && isL1) ? 0.0f : cn_;                                         \
        float hv_ = O_ * tanh_f(cst);                                              \
        if (wr && !((T0) && isL1)) *((P) ? wpt1 : wpt0) = (_Float16)hv_;           \
        __syncthreads();                                                           \
    }

    // t=0 (P=0): L1 c-update & write suppressed (h1(-1) stays 0)
    STEP(0, 1, xq[0])
    // t=1..510 as 255 (odd,even) pairs
    for (int k2 = 0; k2 < 255; ++k2) {
        STEP(1, 0, xq[1])
        STEP(0, 0, xq[2])
        xq += 2;
    }
    // t=511 (P=1): writes h0(511), h1(510) into buf 0
    STEP(1, 0, xq[1])
#undef STEP

    // ---- tail: h1(511) from h0(511), h1(510) (both in buf 0) ----
    {
        f16x8 hb0_ = RD(0, 0, 0), hb1_ = RD(0, 0, 1);
        f16x8 pb0_ = RD(1, 0, 0), pb1_ = RD(1, 0, 1);
        f32x4 z_ = {0.0f, 0.0f, 0.0f, 0.0f};
        f32x4 a1_ = __builtin_amdgcn_mfma_f32_16x16x32_f16(wa_ih1[0], hb0_, z_, 0,0,0);
        a1_ = __builtin_amdgcn_mfma_f32_16x16x32_f16(wa_ih1[1], hb1_, a1_, 0,0,0);
        f32x4 a2_ = __builtin_amdgcn_mfma_f32_16x16x32_f16(wa_hh1[0], pb0_, z_, 0,0,0);
        a2_ = __builtin_amdgcn_mfma_f32_16x16x32_f16(wa_hh1[1], pb1_, a2_, 0,0,0);
        a1_ += a2_;
        float s0_ = __shfl_xor(a1_[0], 8), s1_ = __shfl_xor(a1_[1], 8);
        float s2_ = __shfl_xor(a1_[2], 8), s3_ = __shfl_xor(a1_[3], 8);
        if (isL1 && wr) {
            float g0_ = s0_ + bza[0], g1_ = s1_ + bza[1];
            float g2_ = s2_ + bza[2], g3_ = s3_ + bza[3];
            float I_ = sigm_f(g0_), F_ = sigm_f(g1_);
            float G_ = tanh_f(g2_), O_ = sigm_f(g3_);
            float cn_ = __builtin_fmaf(F_, cst, I_ * G_);
            shf[cb][uc] = O_ * tanh_f(cn_);
        }
    }
    __syncthreads();

    if (tid < MB) {
        float s = b_fc[0];
        for (int j = 0; j < HH; ++j) s += shf[tid][j] * sh_wfc[j];
        out[b0 + tid] = s;
    }
#undef RD
}

extern "C" void kernel_launch(void* const* d_in, const int* in_sizes, int n_in,
                              void* d_out, int out_size, void* d_ws, size_t ws_size,
                              hipStream_t stream) {
    const float* xin   = (const float*)d_in[0];
    const float* W_ih0 = (const float*)d_in[1];
    const float* W_hh0 = (const float*)d_in[2];
    const float* b_ih0 = (const float*)d_in[3];
    const float* b_hh0 = (const float*)d_in[4];
    const float* W_ih1 = (const float*)d_in[5];
    const float* W_hh1 = (const float*)d_in[6];
    const float* b_ih1 = (const float*)d_in[7];
    const float* b_hh1 = (const float*)d_in[8];
    const float* W_fc  = (const float*)d_in[9];
    const float* b_fc  = (const float*)d_in[10];
    float* out = (float*)d_out;

    lstm2_kernel<<<dim3(2048 / MB), dim3(NTHR), 0, stream>>>(
        xin, W_ih0, W_hh0, b_ih0, b_hh0, W_ih1, W_hh1, b_ih1, b_hh1, W_fc, b_fc, out);
}